// Round 8
// baseline (1058.293 us; speedup 1.0000x reference)
//
#include <hip/hip_runtime.h>

typedef unsigned int u32;

#define FEAT 128
#define HID 32
#define EMB 16
#define NEG 0.2f

__device__ __forceinline__ float lrelu(float a) { return a > 0.0f ? a : NEG * a; }

__global__ __launch_bounds__(256) void k_zero(float* p, int n) {
    int i = (int)(blockIdx.x * 256 + threadIdx.x);
    int st = (int)(gridDim.x * 256);
    for (; i < n; i += st) p[i] = 0.0f;
}

// h1 = x @ W1 ; als = h1 . a_src ; ald = h1 . a_dst   (32 lanes per row)
__global__ __launch_bounds__(256) void k_h1(
    const float* __restrict__ x, const float* __restrict__ W1,
    const float* __restrict__ a_s, const float* __restrict__ a_d,
    float* __restrict__ h1, float* __restrict__ als, float* __restrict__ ald, int Nn)
{
    int row = (int)(blockIdx.x * 8 + (threadIdx.x >> 5));
    if (row >= Nn) return;
    int c = threadIdx.x & 31;
    const float* xr = x + (size_t)row * FEAT;
    float acc = 0.0f;
    for (int k = 0; k < FEAT; ++k)
        acc += xr[k] * W1[k * HID + c];
    h1[(size_t)row * HID + c] = acc;
    float ps = acc * a_s[c];
    float pd = acc * a_d[c];
    for (int m = 1; m < 32; m <<= 1) {
        ps += __shfl_xor(ps, m, 32);
        pd += __shfl_xor(pd, m, 32);
    }
    if (c == 0) { als[row] = ps; ald[row] = pd; }
}

// layer-1 edge scatter: 32 lanes per edge (self-loops at tail)
__global__ __launch_bounds__(256) void k_edge1(
    const int* __restrict__ ei, const float* __restrict__ h1,
    const float* __restrict__ als, const float* __restrict__ ald,
    float* __restrict__ acc, float* __restrict__ den, int E_, int EN)
{
    int g = (int)(blockIdx.x * 8 + (threadIdx.x >> 5));
    if (g >= EN) return;
    int t = threadIdx.x & 31;
    int src, dst;
    if (g < E_) { src = ei[g]; dst = ei[(size_t)E_ + g]; }
    else { src = dst = g - E_; }
    float w = __expf(lrelu(als[src] + ald[dst]));
    float v = h1[(size_t)src * HID + t] * w;
    atomicAdd(&acc[(size_t)dst * HID + t], v);
    if (t == 0) atomicAdd(&den[dst], w);
}

// g = relu(acc1/den1 + b1); h2 = g @ W2; als2/ald2   (16 lanes per node)
__global__ __launch_bounds__(256) void k_norm1(
    const float* __restrict__ acc, const float* __restrict__ den,
    const float* __restrict__ b1, const float* __restrict__ W2,
    const float* __restrict__ a_s2, const float* __restrict__ a_d2,
    float* __restrict__ h2, float* __restrict__ als2, float* __restrict__ ald2, int Nn)
{
    const int j = threadIdx.x & 15;
    const int n = (int)((blockIdx.x * blockDim.x + threadIdx.x) >> 4);
    if (n >= Nn) return;
    float inv = 1.0f / den[n];
    float g0 = fmaxf(acc[(size_t)n * HID + j] * inv + b1[j], 0.0f);
    float g1 = fmaxf(acc[(size_t)n * HID + 16 + j] * inv + b1[j + 16], 0.0f);
    float hc = 0.f;
#pragma unroll
    for (int t = 0; t < 16; ++t) hc += __shfl(g0, t, 16) * W2[t * EMB + j];
#pragma unroll
    for (int t = 0; t < 16; ++t) hc += __shfl(g1, t, 16) * W2[(16 + t) * EMB + j];
    h2[(size_t)n * EMB + j] = hc;
    float ps = hc * a_s2[j];
    float pd = hc * a_d2[j];
    for (int m = 1; m < 16; m <<= 1) {
        ps += __shfl_xor(ps, m, 16);
        pd += __shfl_xor(pd, m, 16);
    }
    if (j == 0) { als2[n] = ps; ald2[n] = pd; }
}

// layer-2 edge scatter: 16 lanes per edge
__global__ __launch_bounds__(256) void k_edge2(
    const int* __restrict__ ei, const float* __restrict__ h2,
    const float* __restrict__ als, const float* __restrict__ ald,
    float* __restrict__ acc, float* __restrict__ den, int E_, int EN)
{
    int g = (int)(blockIdx.x * 16 + (threadIdx.x >> 4));
    if (g >= EN) return;
    int t = threadIdx.x & 15;
    int src, dst;
    if (g < E_) { src = ei[g]; dst = ei[(size_t)E_ + g]; }
    else { src = dst = g - E_; }
    float w = __expf(lrelu(als[src] + ald[dst]));
    float v = h2[(size_t)src * EMB + t] * w;
    atomicAdd(&acc[(size_t)dst * EMB + t], v);
    if (t == 0) atomicAdd(&den[dst], w);
}

// out = acc2/den2 + b2   (FLOAT32 output — this was the bug all along)
__global__ __launch_bounds__(256) void k_out(
    const float* __restrict__ acc, const float* __restrict__ den,
    const float* __restrict__ b2, float* __restrict__ out, int Nn)
{
    int idx = (int)(blockIdx.x * 256 + threadIdx.x);
    if (idx >= Nn * EMB) return;
    int n = idx >> 4, c = idx & 15;
    out[idx] = acc[idx] / den[n] + b2[c];
}

extern "C" void kernel_launch(void* const* d_in, const int* in_sizes, int n_in,
                              void* d_out, int out_size, void* d_ws, size_t ws_size,
                              hipStream_t stream)
{
    const float* x   = (const float*)d_in[0];
    const int*   ei  = (const int*)d_in[1];
    // d_in[2] = ew, unused (edge_dim=None)
    const float* W1  = (const float*)d_in[3];
    const float* as1 = (const float*)d_in[4];
    const float* ad1 = (const float*)d_in[5];
    const float* b1  = (const float*)d_in[6];
    const float* W2  = (const float*)d_in[7];
    const float* as2 = (const float*)d_in[8];
    const float* ad2 = (const float*)d_in[9];
    const float* b2  = (const float*)d_in[10];
    float* out = (float*)d_out;

    const int Nn = in_sizes[0] / FEAT;   // 100000
    const int E_ = in_sizes[1] / 2;      // 3200000
    const int EN = E_ + Nn;

    float* h1    = (float*)d_ws;                  // Nn*32
    float* als1  = h1 + (size_t)Nn * HID;         // Nn
    float* ald1  = als1 + Nn;                     // Nn
    float* h2    = ald1 + Nn;                     // Nn*16
    float* als2p = h2 + (size_t)Nn * EMB;         // Nn
    float* ald2p = als2p + Nn;                    // Nn
    float* acc1  = ald2p + Nn;                    // Nn*32  (zeroed)
    float* den1  = acc1 + (size_t)Nn * HID;       // Nn     (zeroed)
    float* acc2  = den1 + Nn;                     // Nn*16  (zeroed)
    float* den2  = acc2 + (size_t)Nn * EMB;       // Nn     (zeroed)

    int zcount = Nn * (HID + 1 + EMB + 1);
    k_zero<<<2048, 256, 0, stream>>>(acc1, zcount);

    k_h1<<<(Nn + 7) / 8, 256, 0, stream>>>(x, W1, as1, ad1, h1, als1, ald1, Nn);
    k_edge1<<<(EN + 7) / 8, 256, 0, stream>>>(ei, h1, als1, ald1, acc1, den1, E_, EN);
    k_norm1<<<(Nn * 16 + 255) / 256, 256, 0, stream>>>(acc1, den1, b1, W2, as2, ad2,
                                                       h2, als2p, ald2p, Nn);
    k_edge2<<<(EN + 15) / 16, 256, 0, stream>>>(ei, h2, als2p, ald2p, acc2, den2, E_, EN);
    k_out<<<(Nn * EMB + 255) / 256, 256, 0, stream>>>(acc2, den2, b2, out, Nn);
}

// Round 9
// 935.791 us; speedup vs baseline: 1.1309x; 1.1309x over previous
//
#include <hip/hip_runtime.h>

#define FEAT 128
#define HID 32
#define EMB 16
#define NEG 0.2f

__device__ __forceinline__ float lrelu(float a) { return a > 0.0f ? a : NEG * a; }

__global__ __launch_bounds__(256) void k_zero_int(int* p, int n) {
    int i = (int)(blockIdx.x * 256 + threadIdx.x);
    if (i < n) p[i] = 0;
}

// histogram of in-degrees
__global__ __launch_bounds__(256) void k_hist(const int* __restrict__ ei, int E_,
                                              int* __restrict__ cnt) {
    int i = (int)(blockIdx.x * 256 + threadIdx.x);
    if (i < E_) atomicAdd(&cnt[ei[(size_t)E_ + i]], 1);
}

// single-block exclusive scan: cnt[0..Nn) -> rowptr[0..Nn], pos copy; rowptr[Nn]=E
__global__ __launch_bounds__(1024) void k_scan(const int* __restrict__ cnt,
                                               int* __restrict__ rowptr,
                                               int* __restrict__ pos, int Nn, int E_) {
    __shared__ int wsum[16];
    __shared__ int carry_s;
    if (threadIdx.x == 0) carry_s = 0;
    __syncthreads();
    int lane = threadIdx.x & 63;
    int wid = (int)(threadIdx.x >> 6);
    int nchunk = (Nn + 1023) / 1024;
    for (int ch = 0; ch < nchunk; ++ch) {
        int i = ch * 1024 + (int)threadIdx.x;
        int v = (i < Nn) ? cnt[i] : 0;
        // wave64 inclusive scan
        int s = v;
        for (int off = 1; off < 64; off <<= 1) {
            int t = __shfl_up(s, off, 64);
            if (lane >= off) s += t;
        }
        if (lane == 63) wsum[wid] = s;
        __syncthreads();
        if (wid == 0 && lane < 16) {
            int p = wsum[lane];
            for (int off = 1; off < 16; off <<= 1) {
                int t = __shfl_up(p, off, 16);
                if ((lane & 15) >= off) p += t;
            }
            wsum[lane] = p;   // inclusive over wave partials
        }
        __syncthreads();
        int woff = (wid > 0) ? wsum[wid - 1] : 0;
        int excl = s - v + woff;
        int carry = carry_s;
        if (i < Nn) { int r = carry + excl; rowptr[i] = r; pos[i] = r; }
        int chunktotal = wsum[15];
        __syncthreads();
        if (threadIdx.x == 0) carry_s = carry + chunktotal;
        __syncthreads();
    }
    if (threadIdx.x == 0) rowptr[Nn] = E_;
}

// scatter src ids into CSR slots
__global__ __launch_bounds__(256) void k_scatter(const int* __restrict__ ei, int E_,
                                                 int* __restrict__ pos,
                                                 int* __restrict__ csr_src) {
    int i = (int)(blockIdx.x * 256 + threadIdx.x);
    if (i >= E_) return;
    int s = ei[i];
    int d = ei[(size_t)E_ + i];
    int p = atomicAdd(&pos[d], 1);
    csr_src[p] = s;
}

// h1 = x @ W1 ; als/ald.  W1 staged in LDS; float4 x loads. 2 rows per wave.
__global__ __launch_bounds__(256) void k_h1(
    const float* __restrict__ x, const float* __restrict__ W1,
    const float* __restrict__ a_s, const float* __restrict__ a_d,
    float* __restrict__ h1, float* __restrict__ als, float* __restrict__ ald, int Nn)
{
    __shared__ float Wl[FEAT * HID];           // 16 KB
    for (int i = threadIdx.x; i < FEAT * HID; i += 256) Wl[i] = W1[i];
    __syncthreads();
    int row = (int)(blockIdx.x * 8 + (threadIdx.x >> 5));
    if (row >= Nn) return;
    int c = threadIdx.x & 31;
    const float asv = a_s[c], adv = a_d[c];
    const float4* xr = (const float4*)(x + (size_t)row * FEAT);
    float acc = 0.0f;
#pragma unroll 8
    for (int k4 = 0; k4 < FEAT / 4; ++k4) {
        float4 xv = xr[k4];
        int k = k4 * 4;
        acc += xv.x * Wl[(k + 0) * HID + c] + xv.y * Wl[(k + 1) * HID + c]
             + xv.z * Wl[(k + 2) * HID + c] + xv.w * Wl[(k + 3) * HID + c];
    }
    h1[(size_t)row * HID + c] = acc;
    float ps = acc * asv, pd = acc * adv;
    for (int m = 1; m < 32; m <<= 1) {
        ps += __shfl_xor(ps, m, 32);
        pd += __shfl_xor(pd, m, 32);
    }
    if (c == 0) { als[row] = ps; ald[row] = pd; }
}

// layer-1 gather-aggregate + norm + relu + (g @ W2) + als2/ald2, fused.
// 32 lanes per node; lane t owns feature t.
__global__ __launch_bounds__(256) void k_agg1(
    const int* __restrict__ rowptr, const int* __restrict__ csr_src,
    const float* __restrict__ h1, const float* __restrict__ als,
    const float* __restrict__ ald, const float* __restrict__ b1,
    const float* __restrict__ W2, const float* __restrict__ a_s2,
    const float* __restrict__ a_d2,
    float* __restrict__ h2, float* __restrict__ als2, float* __restrict__ ald2, int Nn)
{
    int n = (int)(blockIdx.x * 8 + (threadIdx.x >> 5));
    if (n >= Nn) return;
    int t = threadIdx.x & 31;
    float aldn = ald[n];
    // self-loop
    float w = __expf(lrelu(als[n] + aldn));
    float sum = w * h1[(size_t)n * HID + t];
    float den = w;
    int e1 = rowptr[n + 1];
    for (int e = rowptr[n]; e < e1; ++e) {
        int s = csr_src[e];
        float we = __expf(lrelu(als[s] + aldn));
        sum += we * h1[(size_t)s * HID + t];
        den += we;
    }
    float g = fmaxf(sum / den + b1[t], 0.0f);
    // h2[n][j] = sum_t g[t] * W2[t][j];  j duplicated across both 16-halves
    int j = t & 15;
    float hc = 0.0f;
#pragma unroll
    for (int tt = 0; tt < HID; ++tt)
        hc += __shfl(g, tt, 32) * W2[tt * EMB + j];
    if (t < 16) h2[(size_t)n * EMB + j] = hc;
    float ps = hc * a_s2[j], pd = hc * a_d2[j];
    for (int m = 1; m < 16; m <<= 1) {
        ps += __shfl_xor(ps, m, 16);
        pd += __shfl_xor(pd, m, 16);
    }
    if (t == 0) { als2[n] = ps; ald2[n] = pd; }
}

// layer-2 gather-aggregate + bias, writes out directly. 16 lanes per node.
__global__ __launch_bounds__(256) void k_agg2(
    const int* __restrict__ rowptr, const int* __restrict__ csr_src,
    const float* __restrict__ h2, const float* __restrict__ als,
    const float* __restrict__ ald, const float* __restrict__ b2,
    float* __restrict__ out, int Nn)
{
    int n = (int)(blockIdx.x * 16 + (threadIdx.x >> 4));
    if (n >= Nn) return;
    int t = threadIdx.x & 15;
    float aldn = ald[n];
    float w = __expf(lrelu(als[n] + aldn));
    float sum = w * h2[(size_t)n * EMB + t];
    float den = w;
    int e1 = rowptr[n + 1];
    for (int e = rowptr[n]; e < e1; ++e) {
        int s = csr_src[e];
        float we = __expf(lrelu(als[s] + aldn));
        sum += we * h2[(size_t)s * EMB + t];
        den += we;
    }
    out[(size_t)n * EMB + t] = sum / den + b2[t];
}

extern "C" void kernel_launch(void* const* d_in, const int* in_sizes, int n_in,
                              void* d_out, int out_size, void* d_ws, size_t ws_size,
                              hipStream_t stream)
{
    const float* x   = (const float*)d_in[0];
    const int*   ei  = (const int*)d_in[1];
    // d_in[2] = ew, unused (edge_dim=None)
    const float* W1  = (const float*)d_in[3];
    const float* as1 = (const float*)d_in[4];
    const float* ad1 = (const float*)d_in[5];
    const float* b1  = (const float*)d_in[6];
    const float* W2  = (const float*)d_in[7];
    const float* as2 = (const float*)d_in[8];
    const float* ad2 = (const float*)d_in[9];
    const float* b2  = (const float*)d_in[10];
    float* out = (float*)d_out;

    const int Nn = in_sizes[0] / FEAT;   // 100000
    const int E_ = in_sizes[1] / 2;      // 3200000

    // workspace layout
    float* h1    = (float*)d_ws;                  // Nn*32
    float* als1  = h1 + (size_t)Nn * HID;         // Nn
    float* ald1  = als1 + Nn;                     // Nn
    float* h2    = ald1 + Nn;                     // Nn*16
    float* als2p = h2 + (size_t)Nn * EMB;         // Nn
    float* ald2p = als2p + Nn;                    // Nn
    int* cnt     = (int*)(ald2p + Nn);            // Nn      (zeroed)
    int* rowptr  = cnt + Nn;                      // Nn+1
    int* pos     = rowptr + Nn + 1;               // Nn
    int* csr_src = pos + Nn;                      // E_
    // total: 52*Nn floats + (3*Nn+1+E_) ints ≈ 35.6 MB

    const int eb = (E_ + 255) / 256;

    // ---- build CSR (by destination) ----
    k_zero_int<<<(Nn + 255) / 256, 256, 0, stream>>>(cnt, Nn);
    k_hist<<<eb, 256, 0, stream>>>(ei, E_, cnt);
    k_scan<<<1, 1024, 0, stream>>>(cnt, rowptr, pos, Nn, E_);
    k_scatter<<<eb, 256, 0, stream>>>(ei, E_, pos, csr_src);

    // ---- layer 1 ----
    k_h1<<<(Nn + 7) / 8, 256, 0, stream>>>(x, W1, as1, ad1, h1, als1, ald1, Nn);
    k_agg1<<<(Nn + 7) / 8, 256, 0, stream>>>(rowptr, csr_src, h1, als1, ald1,
                                             b1, W2, as2, ad2, h2, als2p, ald2p, Nn);
    // ---- layer 2 ----
    k_agg2<<<(Nn + 15) / 16, 256, 0, stream>>>(rowptr, csr_src, h2, als2p, ald2p,
                                               b2, out, Nn);
}